// Round 6
// baseline (495.629 us; speedup 1.0000x reference)
//
#include <hip/hip_runtime.h>
#include <math.h>

// Problem constants (setup_inputs): B=8, C=64, N=4096, O=64, K=20
#define Bn 8
#define Cc 64
#define Nn 4096
#define Oo 64
#define Kk 20
#define Kq 5                 // quarter-list size (rank-split quad handlers)
#define QCAP 24              // per-row candidate queue capacity per tile
#define NTOT (Bn*Nn*Kk)      // 655360 elements per BN channel

typedef __attribute__((ext_vector_type(8))) short short8;
typedef __attribute__((ext_vector_type(4))) float f32x4;

__device__ __forceinline__ unsigned bf16_rn(float v) {
  unsigned u = __float_as_uint(v);
  return (u + 0x7FFFu + ((u >> 16) & 1)) >> 16;     // RN-even
}

// quad DPP permutes (1-cycle VALU, no lgkm)
template <int P>
__device__ __forceinline__ float qperm_f(float v) {
  return __int_as_float(__builtin_amdgcn_mov_dpp(__float_as_int(v), P, 0xF, 0xF, true));
}
template <int P>
__device__ __forceinline__ int qperm_i(int v) {
  return __builtin_amdgcn_mov_dpp(v, P, 0xF, 0xF, true);
}

// Quarter-split sorted-insert: lane dj of a quad holds ranks 5*dj..5*dj+4 of a
// row's ascending top-20. For candidate (kv,ki): the value entering quarter dj
// is in = max(kv, lmax_0..lmax_{dj-1}) (exactly the sequential evict chain;
// strict '>' updates make ties prefer chain-earlier values). Exclusive
// prefix-max over the quad via 3 quad_perm DPPs; then a 5-deep insert.
// DPPs must run with the whole quad active: all 4 lanes of a quad share the
// same row -> same cn -> same loop trip count, so exec is quad-uniform here.
__device__ __forceinline__ void quad_insert(float (&hk)[Kq], int (&hix)[Kq],
                                            float kv, int ki, int dj, bool valid) {
  float lmax = hk[4];
  int lmi = hix[4];
  float t1 = qperm_f<0x90>(lmax); int i1 = qperm_i<0x90>(lmi);  // [0,0,1,2]
  float t2 = qperm_f<0x40>(lmax); int i2 = qperm_i<0x40>(lmi);  // [0,0,0,1]
  float t3 = qperm_f<0x00>(lmax); int i3 = qperm_i<0x00>(lmi);  // [0,0,0,0]
  float e = t3; int ei = i3;                   // chain priority: lmax0 first
  if (t2 > e) { e = t2; ei = i2; }
  if (t1 > e) { e = t1; ei = i1; }
  bool useE = (dj != 0) && (e > kv);           // dj==0 always takes kv
  float in = useE ? e : kv;
  int ii = useE ? ei : ki;
  if (valid && in < hk[4]) {
    bool c0 = in < hk[0], c1 = in < hk[1], c2 = in < hk[2], c3 = in < hk[3];
    hk[4] = c3 ? hk[3] : in;                hix[4] = c3 ? hix[3] : ii;
    hk[3] = c3 ? (c2 ? hk[2] : in) : hk[3]; hix[3] = c3 ? (c2 ? hix[2] : ii) : hix[3];
    hk[2] = c2 ? (c1 ? hk[1] : in) : hk[2]; hix[2] = c2 ? (c1 ? hix[1] : ii) : hix[2];
    hk[1] = c1 ? (c0 ? hk[0] : in) : hk[1]; hix[1] = c1 ? (c0 ? hix[0] : ii) : hix[1];
    if (c0) { hk[0] = in; hix[0] = ii; }
  }
}

// ---------------------------------------------------------------- k_split
// x fp32 [b][c][n] -> INTERLEAVED 3-term bf16 split xs3[b][n][{h|m|l}*64+c]
// (192 shorts/row), plus sq[b][n].
//   h = RN(x); m = RN(x-h); l = RN(x-h-m)   (x-h, x-h-m exact in fp32)
__global__ __launch_bounds__(256) void k_split(const float* __restrict__ x,
                                               unsigned short* __restrict__ xs3,
                                               float* __restrict__ sqv) {
  __shared__ float xs[64][68];                  // [c][n], float4-friendly pad
  int tid = threadIdx.x;
  int b = blockIdx.x & 7;
  int n0 = (blockIdx.x >> 3) << 6;
  for (int i = 0; i < 4; i++) {
    int c = i * 16 + (tid >> 4);
    int n = (tid & 15) * 4;
    float4 v = *(const float4*)&x[((size_t)b * Cc + c) * Nn + n0 + n];
    *(float4*)&xs[c][n] = v;
  }
  __syncthreads();
  for (int i = 0; i < 4; i++) {
    int n = i * 16 + (tid >> 4);
    int c = (tid & 15) * 4;
    ushort4 h4, m4, l4;
    unsigned short* hp = (unsigned short*)&h4;
    unsigned short* mp = (unsigned short*)&m4;
    unsigned short* lp = (unsigned short*)&l4;
#pragma unroll
    for (int j = 0; j < 4; j++) {
      float v = xs[c + j][n];
      unsigned hb = bf16_rn(v);
      float hf = __uint_as_float(hb << 16);
      float r1 = v - hf;                                     // exact
      unsigned mb = bf16_rn(r1);
      float mf = __uint_as_float(mb << 16);
      float r2 = r1 - mf;                                    // exact
      unsigned lb = bf16_rn(r2);
      hp[j] = (unsigned short)hb;
      mp[j] = (unsigned short)mb;
      lp[j] = (unsigned short)lb;
    }
    size_t o = ((size_t)(b << 12) + n0 + n) * 192 + c;
    *(ushort4*)&xs3[o] = h4;
    *(ushort4*)&xs3[o + 64] = m4;
    *(ushort4*)&xs3[o + 128] = l4;
  }
  if (tid < 64) {
    float s = 0.f;
#pragma unroll
    for (int c = 0; c < 64; c++) { float v = xs[c][tid]; s = fmaf(v, v, s); }
    sqv[b * Nn + n0 + tid] = s;
  }
}

// ---------------------------------------------------------------- k_y1z
__global__ __launch_bounds__(256) void k_y1z(const float* __restrict__ x,
                                             const float* __restrict__ Wm,
                                             float* __restrict__ y1,
                                             float* __restrict__ z) {
  __shared__ float xs[64][68];                  // [c][n]
  __shared__ float Wl[64][129];
  int tid = threadIdx.x;
  int b = blockIdx.x & 7;
  int n0 = (blockIdx.x >> 3) << 6;
  for (int i = tid; i < 64 * 128; i += 256) Wl[i >> 7][i & 127] = Wm[i];
  for (int i = 0; i < 4; i++) {
    int c = i * 16 + (tid >> 4);
    int n = (tid & 15) * 4;
    float4 v = *(const float4*)&x[((size_t)b * Cc + c) * Nn + n0 + n];
    *(float4*)&xs[c][n] = v;
  }
  __syncthreads();
  int o = tid & 63, ng = tid >> 6;              // ng == wave id -> nb uniform
  for (int p = 0; p < 4; p++) {
    int nb = p * 16 + ng * 4;
    float a1[4] = {0.f, 0.f, 0.f, 0.f};
    float a2[4] = {0.f, 0.f, 0.f, 0.f};
#pragma unroll 8
    for (int c = 0; c < 64; c++) {
      float4 xv = *(const float4*)&xs[c][nb];   // wave-broadcast
      float w1v = Wl[o][c], w2v = Wl[o][64 + c];
      float xa[4] = {xv.x, xv.y, xv.z, xv.w};
#pragma unroll
      for (int j = 0; j < 4; j++) {
        a1[j] = fmaf(xa[j], w1v, a1[j]);
        a2[j] = fmaf(xa[j], w2v, a2[j]);
      }
    }
#pragma unroll
    for (int j = 0; j < 4; j++) {
      size_t off = ((size_t)b * Nn + n0 + nb + j) * 64 + o;
      y1[off] = a1[j];
      z[off] = a2[j] - a1[j];
    }
  }
}

// ---------------------------------------------------------------- k_knn (v17)
// R5 evidence: ballot-push cost ~450 VALU/tile (+48us) -> REVERT to v14's
// 16-slot atomicAdd push (atomics serialize on the DS pipe, hidden under
// VALU issue). KEEP swizzled staging (conflicts 13.6x down, harmless) and
// QCAP 24. NEW: QUARTER-SPLIT DRAIN -- 4 lanes per row (16 rows x 4 = all
// 64 lanes active, was 32), 5-deep insert chains (was 10), quad prefix-max
// via 3 DPPs replaces the pair shfl handoff. Also float4 threshold loads.
__global__ __launch_bounds__(512, 4) void k_knn(const unsigned short* __restrict__ xs3,
                                                const float* __restrict__ sqv,
                                                int* __restrict__ idxout) {
  __shared__ alignas(16) short Bs[2][12288];     // [grp][row-major 64x192, XOR-swizzled]
  __shared__ alignas(16) float thrS[2][64];
  __shared__ alignas(16) float sqs[2][64];
  __shared__ alignas(16) float qk[2][64][QCAP];  // 96B rows
  __shared__ alignas(16) unsigned short qm[2][64][QCAP]; // 48B rows
  __shared__ int qcnt[2][64];

  const int tid = threadIdx.x;
  const int lane = tid & 63;
  const int w = tid >> 6;                        // 0..7
  const int grp = w >> 2;                        // m-range group
  const int wg = w & 3;                          // wave within group
  const int tig = tid & 255;                     // thread within group
  const int b = blockIdx.x & 7;                  // XCD swizzle: batch per XCD
  const int n0 = (blockIdx.x >> 3) << 6;         // 64 row-blocks x 64 rows
  const int lm = lane & 15;                      // candidate col / A row slot
  const int q = lane >> 4;                       // quad: C row = q*4+r
  const int rowq = wg * 16 + q * 4;              // my 4 push rows base
  const int drow = wg * 16 + (lane >> 2);        // drain row (16 rows/wave)
  const int dj = lane & 3;                       // quarter index in drain quad

  // quarter-list: sorted ascending 5-list in registers (ranks 5*dj..5*dj+4)
  float hk[Kq];
  int hix[Kq];
#pragma unroll
  for (int kk = 0; kk < Kq; kk++) { hk[kk] = INFINITY; hix[kk] = 0; }

  if (dj == 3) { thrS[grp][drow] = INFINITY; qcnt[grp][drow] = 0; }

  // A fragments: wave owns 16 DISTINCT rows n0 + wg*16 + lm (one wave per
  // group covers each row-set; the two waves scan disjoint m-halves)
  const size_t arow = ((size_t)(b << 12) + n0 + wg * 16 + lm) * 192;
  short8 ah0 = *(const short8*)&xs3[arow + q * 8];
  short8 ah1 = *(const short8*)&xs3[arow + 32 + q * 8];
  short8 am0 = *(const short8*)&xs3[arow + 64 + q * 8];
  short8 am1 = *(const short8*)&xs3[arow + 96 + q * 8];
  short8 al0 = *(const short8*)&xs3[arow + 128 + q * 8];
  short8 al1 = *(const short8*)&xs3[arow + 160 + q * 8];

  // staging: per-thread source pointer + 6 fixed swizzled LDS dests.
  // granule f (16B) of the 64-row window -> LDS short offset (f*8)^((r&7)<<3),
  // r = f/24. Rows change at multiples of 24 (== 0 mod 8) so the XOR is a
  // bijection within each aligned-8-granule (128B) block -> linear writes.
  const unsigned short* gp = xs3 + ((size_t)(b << 12) + grp * 2048) * 192 + tig * 8;
  short* ld[6];
#pragma unroll
  for (int i = 0; i < 6; i++) {
    int f = i * 256 + tig;                       // granule id in [0,1536)
    int r = f / 24;
    ld[i] = &Bs[grp][(f * 8) ^ ((r & 7) << 3)];
  }
  // B-fragment read XOR terms: ((g*16+lm)&7) == (lm&7), constant across g
  const int qa = ((q ^ (lm & 7)) << 3);          // shorts, frag 0 (cols 0-31)
  const int qb = (((q + 4) ^ (lm & 7)) << 3);    // shorts, frag 1 (cols 32-63)
  const short* Bg = &Bs[grp][0];

  f32x4 acc[4];

  for (int t = 0; t < 32; t++) {
    const int m0 = grp * 2048 + t * 64;
    __syncthreads();                              // all waves done reading Bs
#pragma unroll
    for (int i = 0; i < 6; i++) {
      short8 v = *(const short8*)(gp + i * 2048);
      *(short8*)ld[i] = v;
    }
    gp += 12288;                                  // next 64 rows
    if (tig < 16) ((float4*)sqs[grp])[tig] = ((const float4*)(sqv + b * Nn + m0))[tig];
    __syncthreads();                              // staging visible

#pragma unroll
    for (int g = 0; g < 4; g++) {
      const short* brow = Bg + (g * 16 + lm) * 192;
      short8 bh0 = *(const short8*)(brow + qa);
      short8 bh1 = *(const short8*)(brow + qb);
      short8 bm0 = *(const short8*)(brow + 64 + qa);
      short8 bm1 = *(const short8*)(brow + 64 + qb);
      short8 bl0 = *(const short8*)(brow + 128 + qa);
      short8 bl1 = *(const short8*)(brow + 128 + qb);
      f32x4 a = (f32x4){0.f, 0.f, 0.f, 0.f};
      a = __builtin_amdgcn_mfma_f32_16x16x32_bf16(am0, bm0, a, 0, 0, 0);  // mm
      a = __builtin_amdgcn_mfma_f32_16x16x32_bf16(am1, bm1, a, 0, 0, 0);
      a = __builtin_amdgcn_mfma_f32_16x16x32_bf16(ah0, bl0, a, 0, 0, 0);  // hl
      a = __builtin_amdgcn_mfma_f32_16x16x32_bf16(ah1, bl1, a, 0, 0, 0);
      a = __builtin_amdgcn_mfma_f32_16x16x32_bf16(al0, bh0, a, 0, 0, 0);  // lh
      a = __builtin_amdgcn_mfma_f32_16x16x32_bf16(al1, bh1, a, 0, 0, 0);
      a = __builtin_amdgcn_mfma_f32_16x16x32_bf16(ah0, bm0, a, 0, 0, 0);  // hm
      a = __builtin_amdgcn_mfma_f32_16x16x32_bf16(ah1, bm1, a, 0, 0, 0);
      a = __builtin_amdgcn_mfma_f32_16x16x32_bf16(am0, bh0, a, 0, 0, 0);  // mh
      a = __builtin_amdgcn_mfma_f32_16x16x32_bf16(am1, bh1, a, 0, 0, 0);
      a = __builtin_amdgcn_mfma_f32_16x16x32_bf16(ah0, bh0, a, 0, 0, 0);  // hh
      a = __builtin_amdgcn_mfma_f32_16x16x32_bf16(ah1, bh1, a, 0, 0, 0);
      acc[g] = a;
    }

    // keys = sq[m] - 2*dot; all 64 lanes hold unique (row=q*4+r, col)
    unsigned pend = 0;
    {
      float4 t4 = *(const float4*)&thrS[grp][rowq];
      float tl[4] = {t4.x, t4.y, t4.z, t4.w};
      if (grp) {                                  // safe direction only
        float4 s4 = *(const float4*)&thrS[0][rowq];
        tl[0] = fminf(tl[0], s4.x); tl[1] = fminf(tl[1], s4.y);
        tl[2] = fminf(tl[2], s4.z); tl[3] = fminf(tl[3], s4.w);
      }
#pragma unroll
      for (int g = 0; g < 4; g++) {
        float sv = sqs[grp][g * 16 + lm];
#pragma unroll
        for (int r = 0; r < 4; r++) {
          float key = fmaf(-2.f, acc[g][r], sv);
          acc[g][r] = key;
          if (key < tl[r]) pend |= 1u << (g * 4 + r);
        }
      }
    }

    // wave-private push / drain: NO __syncthreads (DS in-order per wave;
    // each wave pushes/drains only its own 16 rows within its group)
    for (;;) {
      if (pend) {
#pragma unroll
        for (int g = 0; g < 4; g++) {
#pragma unroll
          for (int r = 0; r < 4; r++) {
            unsigned bit = 1u << (g * 4 + r);
            if (pend & bit) {
              int row = rowq + r;
              int p = atomicAdd(&qcnt[grp][row], 1);
              if (p < QCAP) {
                qk[grp][row][p] = acc[g][r];
                qm[grp][row][p] = (unsigned short)(m0 + g * 16 + lm);
                pend &= ~bit;
              }
              // else: bit stays set -> retry after drain
            }
          }
        }
      }
      unsigned long long anyovf = __ballot(pend != 0);

      {                                           // quad drain: all 64 lanes
        int cn = qcnt[grp][drow];
        if (cn > QCAP) cn = QCAP;
        for (int p0 = 0; p0 < cn; p0 += 2) {
          float2 kv2 = *(const float2*)&qk[grp][drow][p0];   // quad-broadcast
          ushort2 mv2 = *(const ushort2*)&qm[grp][drow][p0];
          quad_insert(hk, hix, kv2.x, (int)mv2.x, dj, true);
          quad_insert(hk, hix, kv2.y, (int)mv2.y, dj, p0 + 1 < cn);
        }
        if (cn && dj == 3) { qcnt[grp][drow] = 0; thrS[grp][drow] = hk[4]; }
      }
      if (!anyovf) break;
      // refilter surviving bits against the tightened thresholds
      if (pend) {
        float4 t4 = *(const float4*)&thrS[grp][rowq];
        float tl[4] = {t4.x, t4.y, t4.z, t4.w};
        if (grp) {
          float4 s4 = *(const float4*)&thrS[0][rowq];
          tl[0] = fminf(tl[0], s4.x); tl[1] = fminf(tl[1], s4.y);
          tl[2] = fminf(tl[2], s4.z); tl[3] = fminf(tl[3], s4.w);
        }
#pragma unroll
        for (int g = 0; g < 4; g++)
#pragma unroll
          for (int r = 0; r < 4; r++) {
            unsigned bit = 1u << (g * 4 + r);
            if ((pend & bit) && acc[g][r] >= tl[r]) pend &= ~bit;
          }
      }
    }
  }

  // -------- merge: group 1 publishes its rank-sorted 20-list per row
  if (grp == 1) {
#pragma unroll
    for (int kk = 0; kk < Kq; kk++) {
      qk[1][drow][dj * Kq + kk] = hk[kk];
      qm[1][drow][dj * Kq + kk] = (unsigned short)hix[kk];
    }
  }
  __syncthreads();
  if (grp == 0) {
    // feed group 1's 20 candidates (ascending key order) through the same
    // quad machinery; group-1 m-indices are all >= 2048 > any group-0
    // index, so strict '<' keeps sequential-scan tie semantics
    for (int p0 = 0; p0 < Kk; p0 += 2) {
      float2 kv2 = *(const float2*)&qk[1][drow][p0];
      ushort2 mv2 = *(const ushort2*)&qm[1][drow][p0];
      quad_insert(hk, hix, kv2.x, (int)mv2.x, dj, true);
      quad_insert(hk, hix, kv2.y, (int)mv2.y, dj, true);
    }
    // final write: lane dj writes ranks 5*dj..5*dj+4
    size_t obase = ((size_t)b * Nn + n0 + drow) * Kk + dj * Kq;
#pragma unroll
    for (int kk = 0; kk < Kq; kk++) idxout[obase + kk] = hix[kk];
  }
}

// ---------------------------------------------------------------- k_stats
__global__ __launch_bounds__(256) void k_stats(const float* __restrict__ y1,
                                               const float* __restrict__ z,
                                               const int* __restrict__ idxp,
                                               float* __restrict__ parts) {
  __shared__ float rs[4][64];
  __shared__ float rq[4][64];
  int tid = threadIdx.x;
  int o = tid & 63, g = tid >> 6;
  int b = blockIdx.x & 7;                       // XCD swizzle
  int n0 = (blockIdx.x >> 3) << 6;
  const float* y1b = y1 + (size_t)b * Nn * 64;
  float s = 0.f, ss = 0.f;
  for (int t = 0; t < 16; t++) {
    int n = n0 + g + t * 4;
    size_t base = (size_t)b * Nn + n;
    float zv = z[base * 64 + o];
    const int* ip = idxp + base * Kk;
#pragma unroll
    for (int k = 0; k < Kk; k++) {
      int j = ip[k];
      float hv = y1b[(size_t)j * 64 + o] + zv;
      s += hv;
      ss = fmaf(hv, hv, ss);
    }
  }
  rs[g][o] = s;
  rq[g][o] = ss;
  __syncthreads();
  if (tid < 64) {
    parts[(size_t)blockIdx.x * 128 + tid] = rs[0][tid] + rs[1][tid] + rs[2][tid] + rs[3][tid];
    parts[(size_t)blockIdx.x * 128 + 64 + tid] = rq[0][tid] + rq[1][tid] + rq[2][tid] + rq[3][tid];
  }
}

// ---------------------------------------------------------------- k_reduce
__global__ __launch_bounds__(128) void k_reduce(const float* __restrict__ parts,
                                                float* __restrict__ stats) {
  int tid = threadIdx.x;                         // [0,128)
  float s = 0.f;
  for (int i = 0; i < 512; i += 4) {
    s += parts[(size_t)i * 128 + tid] + parts[(size_t)(i + 1) * 128 + tid] +
         parts[(size_t)(i + 2) * 128 + tid] + parts[(size_t)(i + 3) * 128 + tid];
  }
  stats[tid] = s;
}

// ---------------------------------------------------------------- k_out
__global__ __launch_bounds__(256) void k_out(const float* __restrict__ y1,
                                             const float* __restrict__ z,
                                             const int* __restrict__ idxp,
                                             const float* __restrict__ stats,
                                             const float* __restrict__ gamma,
                                             const float* __restrict__ beta,
                                             float* __restrict__ out) {
  __shared__ float T[64][65];
  int tid = threadIdx.x;
  int lane = tid & 63;
  int w = tid >> 6;
  int b = blockIdx.x & 7;                       // XCD swizzle
  int n0 = (blockIdx.x >> 3) << 6;
  int o = lane;
  const float inv = 1.0f / (float)NTOT;
  float mean = stats[o] * inv;
  float var = fmaf(-mean, mean, stats[64 + o] * inv);
  float sc = gamma[o] * rsqrtf(var + 1e-5f);
  float bi = fmaf(-mean, sc, beta[o]);
  const float* y1b = y1 + (size_t)b * Nn * 64;
  for (int t = 0; t < 16; t++) {
    int nl = w + t * 4;
    size_t base = (size_t)b * Nn + n0 + nl;
    float zv = z[base * 64 + o];
    const int* ip = idxp + base * Kk;
    float mv = -INFINITY;
#pragma unroll
    for (int k = 0; k < Kk; k++) {
      int j = ip[k];
      float hv = y1b[(size_t)j * 64 + o] + zv;
      float hn = fmaf(hv, sc, bi);
      float a = (hn >= 0.f) ? hn : 0.2f * hn;
      mv = fmaxf(mv, a);
    }
    T[o][nl] = mv;
  }
  __syncthreads();
  for (int t = 0; t < 16; t++) {
    int oo = w * 16 + t;
    out[((size_t)b * Oo + oo) * Nn + n0 + lane] = T[oo][lane];
  }
}

// ---------------------------------------------------------------- launch
extern "C" void kernel_launch(void* const* d_in, const int* in_sizes, int n_in,
                              void* d_out, int out_size, void* d_ws, size_t ws_size,
                              hipStream_t stream) {
  const float* x = (const float*)d_in[0];
  const float* W = (const float*)d_in[1];
  const float* gamma = (const float*)d_in[2];
  const float* beta = (const float*)d_in[3];
  // d_in[4] is k (=20), baked in as Kk.

  // workspace layout (bytes):
  //   xs3  : [0,       12582912)  bf16 interleaved [b][n][3*64]  (dead after
  //                                k_knn; y1 overlays [0,8M), z [8M,16M))
  //   y1   : [0,        8388608)  B*N*O fp32  (k_y1z, after k_knn)
  //   z    : [8388608, 16777216)  B*N*O fp32  (k_y1z, after k_knn)
  //   sq   : [16777216,16908288)  B*N fp32
  //   stats: [16908288,16908800)  128 fp32
  //   idx20: [16908800,19530240)  B*N*K int32
  //   parts: [19530240,19792384)  512*128 fp32
  char* ws = (char*)d_ws;
  unsigned short* xs3 = (unsigned short*)ws;
  float* y1 = (float*)ws;
  float* z = (float*)(ws + 8388608);
  float* sq = (float*)(ws + 16777216);
  float* stats = (float*)(ws + 16908288);
  int* idx = (int*)(ws + 16908800);
  float* parts = (float*)(ws + 19530240);
  float* out = (float*)d_out;

  k_split<<<Bn * (Nn / 64), 256, 0, stream>>>(x, xs3, sq);
  k_knn<<<Bn * (Nn / 64), 512, 0, stream>>>(xs3, sq, idx);
  k_y1z<<<Bn * (Nn / 64), 256, 0, stream>>>(x, W, y1, z);
  k_stats<<<Bn * (Nn / 64), 256, 0, stream>>>(y1, z, idx, parts);
  k_reduce<<<1, 128, 0, stream>>>(parts, stats);
  k_out<<<Bn * (Nn / 64), 256, 0, stream>>>(y1, z, idx, stats, gamma, beta, out);
}

// Round 7
// 364.894 us; speedup vs baseline: 1.3583x; 1.3583x over previous
//
#include <hip/hip_runtime.h>
#include <math.h>

// Problem constants (setup_inputs): B=8, C=64, N=4096, O=64, K=20
#define Bn 8
#define Cc 64
#define Nn 4096
#define Oo 64
#define Kk 20
#define Kh 10                // half-list size (rank-split pair handlers)
#define QCAP 24              // per-row candidate queue capacity per tile
#define NTOT (Bn*Nn*Kk)      // 655360 elements per BN channel

typedef __attribute__((ext_vector_type(8))) short short8;
typedef __attribute__((ext_vector_type(4))) float f32x4;

__device__ __forceinline__ unsigned bf16_rn(float v) {
  unsigned u = __float_as_uint(v);
  return (u + 0x7FFFu + ((u >> 16) & 1)) >> 16;     // RN-even
}

// lane-pair swap (lane 2k <-> 2k+1) via DPP quad_perm [1,0,3,2]:
// 1-cycle VALU, no lgkm round-trip (vs ds_bpermute from __shfl_xor)
__device__ __forceinline__ float pair_swap_f(float v) {
  return __int_as_float(__builtin_amdgcn_mov_dpp(__float_as_int(v), 0xB1, 0xF, 0xF, true));
}
__device__ __forceinline__ int pair_swap_i(int v) {
  return __builtin_amdgcn_mov_dpp(v, 0xB1, 0xF, 0xF, true);
}

// async global->LDS, 16B per lane: LDS dest = wave-uniform base + lane*16,
// global src is per-lane. Size must be a literal (16).
__device__ __forceinline__ void gload_lds16(const void* g, void* l) {
  __builtin_amdgcn_global_load_lds((const __attribute__((address_space(1))) void*)g,
                                   (__attribute__((address_space(3))) void*)l,
                                   16, 0, 0);
}

// ---------------------------------------------------------------- k_split
// x fp32 [b][c][n] -> INTERLEAVED 3-term bf16 split xs3[b][n][{h|m|l}*64+c]
// (192 shorts/row), plus sq[b][n].
//   h = RN(x); m = RN(x-h); l = RN(x-h-m)   (x-h, x-h-m exact in fp32)
__global__ __launch_bounds__(256) void k_split(const float* __restrict__ x,
                                               unsigned short* __restrict__ xs3,
                                               float* __restrict__ sqv) {
  __shared__ float xs[64][68];                  // [c][n], float4-friendly pad
  int tid = threadIdx.x;
  int b = blockIdx.x & 7;
  int n0 = (blockIdx.x >> 3) << 6;
  for (int i = 0; i < 4; i++) {
    int c = i * 16 + (tid >> 4);
    int n = (tid & 15) * 4;
    float4 v = *(const float4*)&x[((size_t)b * Cc + c) * Nn + n0 + n];
    *(float4*)&xs[c][n] = v;
  }
  __syncthreads();
  for (int i = 0; i < 4; i++) {
    int n = i * 16 + (tid >> 4);
    int c = (tid & 15) * 4;
    ushort4 h4, m4, l4;
    unsigned short* hp = (unsigned short*)&h4;
    unsigned short* mp = (unsigned short*)&m4;
    unsigned short* lp = (unsigned short*)&l4;
#pragma unroll
    for (int j = 0; j < 4; j++) {
      float v = xs[c + j][n];
      unsigned hb = bf16_rn(v);
      float hf = __uint_as_float(hb << 16);
      float r1 = v - hf;                                     // exact
      unsigned mb = bf16_rn(r1);
      float mf = __uint_as_float(mb << 16);
      float r2 = r1 - mf;                                    // exact
      unsigned lb = bf16_rn(r2);
      hp[j] = (unsigned short)hb;
      mp[j] = (unsigned short)mb;
      lp[j] = (unsigned short)lb;
    }
    size_t o = ((size_t)(b << 12) + n0 + n) * 192 + c;
    *(ushort4*)&xs3[o] = h4;
    *(ushort4*)&xs3[o + 64] = m4;
    *(ushort4*)&xs3[o + 128] = l4;
  }
  if (tid < 64) {
    float s = 0.f;
#pragma unroll
    for (int c = 0; c < 64; c++) { float v = xs[c][tid]; s = fmaf(v, v, s); }
    sqv[b * Nn + n0 + tid] = s;
  }
}

// ---------------------------------------------------------------- k_y1z
__global__ __launch_bounds__(256) void k_y1z(const float* __restrict__ x,
                                             const float* __restrict__ Wm,
                                             float* __restrict__ y1,
                                             float* __restrict__ z) {
  __shared__ float xs[64][68];                  // [c][n]
  __shared__ float Wl[64][129];
  int tid = threadIdx.x;
  int b = blockIdx.x & 7;
  int n0 = (blockIdx.x >> 3) << 6;
  for (int i = tid; i < 64 * 128; i += 256) Wl[i >> 7][i & 127] = Wm[i];
  for (int i = 0; i < 4; i++) {
    int c = i * 16 + (tid >> 4);
    int n = (tid & 15) * 4;
    float4 v = *(const float4*)&x[((size_t)b * Cc + c) * Nn + n0 + n];
    *(float4*)&xs[c][n] = v;
  }
  __syncthreads();
  int o = tid & 63, ng = tid >> 6;              // ng == wave id -> nb uniform
  for (int p = 0; p < 4; p++) {
    int nb = p * 16 + ng * 4;
    float a1[4] = {0.f, 0.f, 0.f, 0.f};
    float a2[4] = {0.f, 0.f, 0.f, 0.f};
#pragma unroll 8
    for (int c = 0; c < 64; c++) {
      float4 xv = *(const float4*)&xs[c][nb];   // wave-broadcast
      float w1v = Wl[o][c], w2v = Wl[o][64 + c];
      float xa[4] = {xv.x, xv.y, xv.z, xv.w};
#pragma unroll
      for (int j = 0; j < 4; j++) {
        a1[j] = fmaf(xa[j], w1v, a1[j]);
        a2[j] = fmaf(xa[j], w2v, a2[j]);
      }
    }
#pragma unroll
    for (int j = 0; j < 4; j++) {
      size_t off = ((size_t)b * Nn + n0 + nb + j) * 64 + o;
      y1[off] = a1[j];
      z[off] = a2[j] - a1[j];
    }
  }
}

// ---------------------------------------------------------------- k_knn (v18)
// Recomposition of all PROVEN-GOOD pieces (r3-r6 evidence):
//  - v14 core: atomicAdd push, PAIR handlers (L=ranks 0-9 / H=10-19),
//    unroll-2 drain, DPP pair swap.  [ballot push +48us VALU (r5); quad
//    drain +100us (r6) -- both reverted]
//  - v16 XOR-linear Bs layout (bank conflicts 1.87e7 -> 1.4e6, reads clean)
//  - NEW: global_load_lds staging. The XOR-linear layout is lane-linear per
//    wave, so each wave issues 6 async 16B direct-to-LDS loads (wave-uniform
//    LDS base + lane*16; per-lane global addr carries the inverse swizzle --
//    the XOR map is an involution). No VGPR round-trip (r4's spill trap
//    avoided: ZERO staging registers), shorter barrier window.
__global__ __launch_bounds__(512, 4) void k_knn(const unsigned short* __restrict__ xs3,
                                                const float* __restrict__ sqv,
                                                int* __restrict__ idxout) {
  __shared__ alignas(16) short Bs[2][12288];     // [grp][row-major 64x192, XOR-swizzled]
  __shared__ alignas(16) float thrS[2][64];
  __shared__ alignas(16) float sqs[2][64];
  __shared__ alignas(16) float qk[2][64][QCAP];  // 96B rows
  __shared__ alignas(16) unsigned short qm[2][64][QCAP]; // 48B rows
  __shared__ int qcnt[2][64];

  const int tid = threadIdx.x;
  const int lane = tid & 63;
  const int w = tid >> 6;                        // 0..7
  const int grp = w >> 2;                        // m-range group
  const int wg = w & 3;                          // wave within group
  const int tig = tid & 255;                     // thread within group
  const int b = blockIdx.x & 7;                  // XCD swizzle: batch per XCD
  const int n0 = (blockIdx.x >> 3) << 6;         // 64 row-blocks x 64 rows
  const int lm = lane & 15;                      // candidate col / A row slot
  const int q = lane >> 4;                       // quad: C row = q*4+r
  const bool handler = (lane < 32);
  const int hrow = wg * 16 + (lane >> 1);        // row for this handler pair
  const bool isL = (lane & 1) == 0;              // L = ranks 0-9, H = 10-19
  const int rowq = wg * 16 + q * 4;              // my 4 push rows base

  // handler half-list: sorted ascending 10-list in registers
  float hk[Kh];
  int hix[Kh];
#pragma unroll
  for (int kk = 0; kk < Kh; kk++) { hk[kk] = INFINITY; hix[kk] = 0; }

  if (handler && !isL) { thrS[grp][hrow] = INFINITY; qcnt[grp][hrow] = 0; }

  // A fragments: wave owns 16 DISTINCT rows n0 + wg*16 + lm (one wave per
  // group covers each row-set; the two waves scan disjoint m-halves)
  const size_t arow = ((size_t)(b << 12) + n0 + wg * 16 + lm) * 192;
  short8 ah0 = *(const short8*)&xs3[arow + q * 8];
  short8 ah1 = *(const short8*)&xs3[arow + 32 + q * 8];
  short8 am0 = *(const short8*)&xs3[arow + 64 + q * 8];
  short8 am1 = *(const short8*)&xs3[arow + 96 + q * 8];
  short8 al0 = *(const short8*)&xs3[arow + 128 + q * 8];
  short8 al1 = *(const short8*)&xs3[arow + 160 + q * 8];

  // ---- global_load_lds staging setup.
  // Global tile = 1536 granules (16B). LDS granule p holds global granule
  // p ^ ((p/24)&7)  (involution; rows are 24 granules, 8-aligned blocks are
  // row-pure, so the XOR never crosses a row). Wave (grp,wg), chunk i:
  // LDS granules [i*256 + wg*64, +64) -- lane l takes p = that + l, fetches
  // global granule p^((p/24)&7). LDS base is wave-uniform; HW adds lane*16.
  const unsigned short* gbase = xs3 + ((size_t)(b << 12) + grp * 2048) * 192;
  int gofs[6];                                   // per-lane global short offs
  short* lbase[6];                               // wave-uniform LDS bases
#pragma unroll
  for (int i = 0; i < 6; i++) {
    int p = i * 256 + wg * 64 + lane;
    int gsrc = p ^ ((p / 24) & 7);
    gofs[i] = gsrc * 8;
    lbase[i] = &Bs[grp][(i * 256 + wg * 64) * 8];
  }
  // B-fragment read XOR terms: ((g*16+lm)&7) == (lm&7), constant across g
  const int qa = ((q ^ (lm & 7)) << 3);          // shorts, frag 0 (cols 0-31)
  const int qb = (((q + 4) ^ (lm & 7)) << 3);    // shorts, frag 1 (cols 32-63)
  const short* Bg = &Bs[grp][0];

  f32x4 acc[4];

  for (int t = 0; t < 32; t++) {
    const int m0 = grp * 2048 + t * 64;
    __syncthreads();                              // all waves done reading Bs
#pragma unroll
    for (int i = 0; i < 6; i++) gload_lds16(gbase + gofs[i], lbase[i]);
    if (tig < 16) gload_lds16(sqv + b * Nn + m0 + lane * 4, &sqs[grp][0]);
    gbase += 12288;                               // next 64 rows
    __syncthreads();                              // vmcnt drained, staging visible

#pragma unroll
    for (int g = 0; g < 4; g++) {
      const short* brow = Bg + (g * 16 + lm) * 192;
      short8 bh0 = *(const short8*)(brow + qa);
      short8 bh1 = *(const short8*)(brow + qb);
      short8 bm0 = *(const short8*)(brow + 64 + qa);
      short8 bm1 = *(const short8*)(brow + 64 + qb);
      short8 bl0 = *(const short8*)(brow + 128 + qa);
      short8 bl1 = *(const short8*)(brow + 128 + qb);
      f32x4 a = (f32x4){0.f, 0.f, 0.f, 0.f};
      a = __builtin_amdgcn_mfma_f32_16x16x32_bf16(am0, bm0, a, 0, 0, 0);  // mm
      a = __builtin_amdgcn_mfma_f32_16x16x32_bf16(am1, bm1, a, 0, 0, 0);
      a = __builtin_amdgcn_mfma_f32_16x16x32_bf16(ah0, bl0, a, 0, 0, 0);  // hl
      a = __builtin_amdgcn_mfma_f32_16x16x32_bf16(ah1, bl1, a, 0, 0, 0);
      a = __builtin_amdgcn_mfma_f32_16x16x32_bf16(al0, bh0, a, 0, 0, 0);  // lh
      a = __builtin_amdgcn_mfma_f32_16x16x32_bf16(al1, bh1, a, 0, 0, 0);
      a = __builtin_amdgcn_mfma_f32_16x16x32_bf16(ah0, bm0, a, 0, 0, 0);  // hm
      a = __builtin_amdgcn_mfma_f32_16x16x32_bf16(ah1, bm1, a, 0, 0, 0);
      a = __builtin_amdgcn_mfma_f32_16x16x32_bf16(am0, bh0, a, 0, 0, 0);  // mh
      a = __builtin_amdgcn_mfma_f32_16x16x32_bf16(am1, bh1, a, 0, 0, 0);
      a = __builtin_amdgcn_mfma_f32_16x16x32_bf16(ah0, bh0, a, 0, 0, 0);  // hh
      a = __builtin_amdgcn_mfma_f32_16x16x32_bf16(ah1, bh1, a, 0, 0, 0);
      acc[g] = a;
    }

    // keys = sq[m] - 2*dot; all 64 lanes hold unique (row=q*4+r, col)
    unsigned pend = 0;
    {
      float4 t4 = *(const float4*)&thrS[grp][rowq];
      float tl[4] = {t4.x, t4.y, t4.z, t4.w};
      if (grp) {                                  // safe direction only
        float4 s4 = *(const float4*)&thrS[0][rowq];
        tl[0] = fminf(tl[0], s4.x); tl[1] = fminf(tl[1], s4.y);
        tl[2] = fminf(tl[2], s4.z); tl[3] = fminf(tl[3], s4.w);
      }
#pragma unroll
      for (int g = 0; g < 4; g++) {
        float sv = sqs[grp][g * 16 + lm];
#pragma unroll
        for (int r = 0; r < 4; r++) {
          float key = fmaf(-2.f, acc[g][r], sv);
          acc[g][r] = key;
          if (key < tl[r]) pend |= 1u << (g * 4 + r);
        }
      }
    }

    // wave-private push / drain: NO __syncthreads (DS in-order per wave;
    // each wave pushes/drains only its own 16 rows within its group)
    for (;;) {
      if (pend) {
#pragma unroll
        for (int g = 0; g < 4; g++) {
#pragma unroll
          for (int r = 0; r < 4; r++) {
            unsigned bit = 1u << (g * 4 + r);
            if (pend & bit) {
              int row = rowq + r;
              int p = atomicAdd(&qcnt[grp][row], 1);
              if (p < QCAP) {
                qk[grp][row][p] = acc[g][r];
                qm[grp][row][p] = (unsigned short)(m0 + g * 16 + lm);
                pend &= ~bit;
              }
              // else: bit stays set -> retry after drain
            }
          }
        }
      }
      unsigned long long anyovf = __ballot(pend != 0);

      if (handler) {                             // 32 lanes: 16 rows x (L,H)
        int cn = qcnt[grp][hrow];                // same for both pair lanes
        if (cn > QCAP) cn = QCAP;
        for (int p0 = 0; p0 < cn; p0 += 2) {
          float2 kv2 = *(const float2*)&qk[grp][hrow][p0];   // pair-broadcast
          ushort2 mv2 = *(const ushort2*)&qm[grp][hrow][p0];
          float kva[2] = {kv2.x, kv2.y};
          unsigned short mva[2] = {mv2.x, mv2.y};
#pragma unroll
          for (int j = 0; j < 2; j++) {
            bool valid = (p0 + j < cn);
            float kv = kva[j];
            int ki = (int)mva[j];
            // L decides what flows to H: its evicted max, or kv itself
            bool lins = kv < hk[Kh - 1];
            float pv_ = lins ? hk[Kh - 1] : kv;
            int pi_ = lins ? hix[Kh - 1] : ki;
            float rv = pair_swap_f(pv_);
            int ri = pair_swap_i(pi_);
            float mval = isL ? kv : rv;
            int midx = isL ? ki : ri;
            if (valid && mval < hk[Kh - 1]) {    // both roles: same 10-insert
              bool cm[Kh];
#pragma unroll
              for (int kk = 0; kk < Kh; kk++) cm[kk] = mval < hk[kk];
#pragma unroll
              for (int kk = Kh - 1; kk >= 1; kk--) {
                hk[kk]  = cm[kk] ? (cm[kk - 1] ? hk[kk - 1]  : mval) : hk[kk];
                hix[kk] = cm[kk] ? (cm[kk - 1] ? hix[kk - 1] : midx) : hix[kk];
              }
              if (cm[0]) { hk[0] = mval; hix[0] = midx; }
            }
          }
        }
        if (cn && !isL) { qcnt[grp][hrow] = 0; thrS[grp][hrow] = hk[Kh - 1]; }
      }
      if (!anyovf) break;
      // refilter surviving bits against the tightened thresholds
      if (pend) {
        float4 t4 = *(const float4*)&thrS[grp][rowq];
        float tl[4] = {t4.x, t4.y, t4.z, t4.w};
        if (grp) {
          float4 s4 = *(const float4*)&thrS[0][rowq];
          tl[0] = fminf(tl[0], s4.x); tl[1] = fminf(tl[1], s4.y);
          tl[2] = fminf(tl[2], s4.z); tl[3] = fminf(tl[3], s4.w);
        }
#pragma unroll
        for (int g = 0; g < 4; g++)
#pragma unroll
          for (int r = 0; r < 4; r++) {
            unsigned bit = 1u << (g * 4 + r);
            if ((pend & bit) && acc[g][r] >= tl[r]) pend &= ~bit;
          }
      }
    }
  }

  // -------- merge: group 1 publishes its rank-sorted 20-list per row
  if (grp == 1 && handler) {
    int base = isL ? 0 : Kh;
#pragma unroll
    for (int kk = 0; kk < Kh; kk++) {
      qk[1][hrow][base + kk] = hk[kk];
      qm[1][hrow][base + kk] = (unsigned short)hix[kk];
    }
  }
  __syncthreads();
  if (grp == 0 && handler) {
    // feed group 1's 20 candidates (ascending key order) through the same
    // pair-insert machinery; group-1 m-indices are all >= 2048 > any
    // group-0 index, so strict '<' keeps sequential-scan tie semantics
    for (int p0 = 0; p0 < Kk; p0 += 4) {
      float4 kv4 = *(const float4*)&qk[1][hrow][p0];
      ushort4 mv4 = *(const ushort4*)&qm[1][hrow][p0];
      float kva[4] = {kv4.x, kv4.y, kv4.z, kv4.w};
      unsigned short mva[4] = {mv4.x, mv4.y, mv4.z, mv4.w};
#pragma unroll
      for (int j = 0; j < 4; j++) {
        float kv = kva[j];
        int ki = (int)mva[j];
        bool lins = kv < hk[Kh - 1];
        float pv_ = lins ? hk[Kh - 1] : kv;
        int pi_ = lins ? hix[Kh - 1] : ki;
        float rv = pair_swap_f(pv_);
        int ri = pair_swap_i(pi_);
        float mval = isL ? kv : rv;
        int midx = isL ? ki : ri;
        if (mval < hk[Kh - 1]) {
          bool cm[Kh];
#pragma unroll
          for (int kk = 0; kk < Kh; kk++) cm[kk] = mval < hk[kk];
#pragma unroll
          for (int kk = Kh - 1; kk >= 1; kk--) {
            hk[kk]  = cm[kk] ? (cm[kk - 1] ? hk[kk - 1]  : mval) : hk[kk];
            hix[kk] = cm[kk] ? (cm[kk - 1] ? hix[kk - 1] : midx) : hix[kk];
          }
          if (cm[0]) { hk[0] = mval; hix[0] = midx; }
        }
      }
    }
    // final write: L lane writes ranks 0-9, H lane ranks 10-19
    size_t obase = ((size_t)b * Nn + n0 + hrow) * Kk + (isL ? 0 : Kh);
#pragma unroll
    for (int kk = 0; kk < Kh; kk++) idxout[obase + kk] = hix[kk];
  }
}

// ---------------------------------------------------------------- k_stats
__global__ __launch_bounds__(256) void k_stats(const float* __restrict__ y1,
                                               const float* __restrict__ z,
                                               const int* __restrict__ idxp,
                                               float* __restrict__ parts) {
  __shared__ float rs[4][64];
  __shared__ float rq[4][64];
  int tid = threadIdx.x;
  int o = tid & 63, g = tid >> 6;
  int b = blockIdx.x & 7;                       // XCD swizzle
  int n0 = (blockIdx.x >> 3) << 6;
  const float* y1b = y1 + (size_t)b * Nn * 64;
  float s = 0.f, ss = 0.f;
  for (int t = 0; t < 16; t++) {
    int n = n0 + g + t * 4;
    size_t base = (size_t)b * Nn + n;
    float zv = z[base * 64 + o];
    const int* ip = idxp + base * Kk;
#pragma unroll
    for (int k = 0; k < Kk; k++) {
      int j = ip[k];
      float hv = y1b[(size_t)j * 64 + o] + zv;
      s += hv;
      ss = fmaf(hv, hv, ss);
    }
  }
  rs[g][o] = s;
  rq[g][o] = ss;
  __syncthreads();
  if (tid < 64) {
    parts[(size_t)blockIdx.x * 128 + tid] = rs[0][tid] + rs[1][tid] + rs[2][tid] + rs[3][tid];
    parts[(size_t)blockIdx.x * 128 + 64 + tid] = rq[0][tid] + rq[1][tid] + rq[2][tid] + rq[3][tid];
  }
}

// ---------------------------------------------------------------- k_reduce
__global__ __launch_bounds__(128) void k_reduce(const float* __restrict__ parts,
                                                float* __restrict__ stats) {
  int tid = threadIdx.x;                         // [0,128)
  float s = 0.f;
  for (int i = 0; i < 512; i += 4) {
    s += parts[(size_t)i * 128 + tid] + parts[(size_t)(i + 1) * 128 + tid] +
         parts[(size_t)(i + 2) * 128 + tid] + parts[(size_t)(i + 3) * 128 + tid];
  }
  stats[tid] = s;
}

// ---------------------------------------------------------------- k_out
__global__ __launch_bounds__(256) void k_out(const float* __restrict__ y1,
                                             const float* __restrict__ z,
                                             const int* __restrict__ idxp,
                                             const float* __restrict__ stats,
                                             const float* __restrict__ gamma,
                                             const float* __restrict__ beta,
                                             float* __restrict__ out) {
  __shared__ float T[64][65];
  int tid = threadIdx.x;
  int lane = tid & 63;
  int w = tid >> 6;
  int b = blockIdx.x & 7;                       // XCD swizzle
  int n0 = (blockIdx.x >> 3) << 6;
  int o = lane;
  const float inv = 1.0f / (float)NTOT;
  float mean = stats[o] * inv;
  float var = fmaf(-mean, mean, stats[64 + o] * inv);
  float sc = gamma[o] * rsqrtf(var + 1e-5f);
  float bi = fmaf(-mean, sc, beta[o]);
  const float* y1b = y1 + (size_t)b * Nn * 64;
  for (int t = 0; t < 16; t++) {
    int nl = w + t * 4;
    size_t base = (size_t)b * Nn + n0 + nl;
    float zv = z[base * 64 + o];
    const int* ip = idxp + base * Kk;
    float mv = -INFINITY;
#pragma unroll
    for (int k = 0; k < Kk; k++) {
      int j = ip[k];
      float hv = y1b[(size_t)j * 64 + o] + zv;
      float hn = fmaf(hv, sc, bi);
      float a = (hn >= 0.f) ? hn : 0.2f * hn;
      mv = fmaxf(mv, a);
    }
    T[o][nl] = mv;
  }
  __syncthreads();
  for (int t = 0; t < 16; t++) {
    int oo = w * 16 + t;
    out[((size_t)b * Oo + oo) * Nn + n0 + lane] = T[oo][lane];
  }
}

// ---------------------------------------------------------------- launch
extern "C" void kernel_launch(void* const* d_in, const int* in_sizes, int n_in,
                              void* d_out, int out_size, void* d_ws, size_t ws_size,
                              hipStream_t stream) {
  const float* x = (const float*)d_in[0];
  const float* W = (const float*)d_in[1];
  const float* gamma = (const float*)d_in[2];
  const float* beta = (const float*)d_in[3];
  // d_in[4] is k (=20), baked in as Kk.

  // workspace layout (bytes):
  //   xs3  : [0,       12582912)  bf16 interleaved [b][n][3*64]  (dead after
  //                                k_knn; y1 overlays [0,8M), z [8M,16M))
  //   y1   : [0,        8388608)  B*N*O fp32  (k_y1z, after k_knn)
  //   z    : [8388608, 16777216)  B*N*O fp32  (k_y1z, after k_knn)
  //   sq   : [16777216,16908288)  B*N fp32
  //   stats: [16908288,16908800)  128 fp32
  //   idx20: [16908800,19530240)  B*N*K int32
  //   parts: [19530240,19792384)  512*128 fp32
  char* ws = (char*)d_ws;
  unsigned short* xs3 = (unsigned short*)ws;
  float* y1 = (float*)ws;
  float* z = (float*)(ws + 8388608);
  float* sq = (float*)(ws + 16777216);
  float* stats = (float*)(ws + 16908288);
  int* idx = (int*)(ws + 16908800);
  float* parts = (float*)(ws + 19530240);
  float* out = (float*)d_out;

  k_split<<<Bn * (Nn / 64), 256, 0, stream>>>(x, xs3, sq);
  k_knn<<<Bn * (Nn / 64), 512, 0, stream>>>(xs3, sq, idx);
  k_y1z<<<Bn * (Nn / 64), 256, 0, stream>>>(x, W, y1, z);
  k_stats<<<Bn * (Nn / 64), 256, 0, stream>>>(y1, z, idx, parts);
  k_reduce<<<1, 128, 0, stream>>>(parts, stats);
  k_out<<<Bn * (Nn / 64), 256, 0, stream>>>(y1, z, idx, stats, gamma, beta, out);
}